// Round 1
// baseline (198.117 us; speedup 1.0000x reference)
//
#include <hip/hip_runtime.h>
#include <math.h>

#define NATOMS 5
#define NEXP 18
#define NBEAD 4
#define EPSV 1e-8f
#define ML2 (0.02f * 0.02f)

// Pack trip(i,j,k) + validity into 16 bits per (expert,bead,t):
//   bits [0:3)=i, [3:6)=j, [6:9)=k (clamped to [0,4]), bit 9 = trip_ok && base_valid.
// 8 t-entries per (expert,bead) combo -> one int4 (16B) per combo.
__global__ void pack_tables(const int* __restrict__ trip, const int* __restrict__ valid,
                            int4* __restrict__ ptbl) {
    int c = blockIdx.x * blockDim.x + threadIdx.x;
    if (c < NEXP * NBEAD) {
        unsigned wv[4] = {0u, 0u, 0u, 0u};
#pragma unroll
        for (int t = 0; t < 8; t++) {
            int b = c * 8 + t;
            int i = trip[b * 3 + 0], j = trip[b * 3 + 1], k = trip[b * 3 + 2];
            int ok = (i >= 0 && j >= 0 && k >= 0 && valid[b] > 0) ? 1 : 0;
            int ic = min(max(i, 0), NATOMS - 1);
            int jc = min(max(j, 0), NATOMS - 1);
            int kc = min(max(k, 0), NATOMS - 1);
            unsigned e = (unsigned)ic | ((unsigned)jc << 3) | ((unsigned)kc << 6) |
                         ((unsigned)ok << 9);
            wv[t >> 1] |= e << ((t & 1) * 16);
        }
        ptbl[c] = make_int4((int)wv[0], (int)wv[1], (int)wv[2], (int)wv[3]);
    }
}

// Select atom idx (0..4) from a register-resident [5][3] array -> v_cndmask chains.
__device__ __forceinline__ void sel5(const float* a, int idx, float& vx, float& vy, float& vz) {
    vx = a[0]; vy = a[1]; vz = a[2];
#pragma unroll
    for (int q = 1; q < 5; q++) {
        bool c = (idx == q);
        vx = c ? a[3 * q + 0] : vx;
        vy = c ? a[3 * q + 1] : vy;
        vz = c ? a[3 * q + 2] : vz;
    }
}

__global__ __launch_bounds__(256) void loss_kernel(
    const float* __restrict__ xin, const float* __restrict__ y_true,
    const float* __restrict__ y_pred, const float* __restrict__ mask,
    const int4* __restrict__ ptbl, float* __restrict__ out, int n, float inv_n) {
    __shared__ float sT[3840];  // 256 rows x 15
    __shared__ float sP[3840];
    __shared__ float sM[3840];
    __shared__ float red[4];

    const int row0 = blockIdx.x * 256;
    int rows = n - row0;
    if (rows > 256) rows = 256;
    const int cnt = rows * 15;
    const int cnt4 = cnt >> 2;

    // Coalesced float4 staging (block base = row0*60 bytes, 16B-aligned).
    const float4* gt = reinterpret_cast<const float4*>(y_true + (size_t)row0 * 15);
    const float4* gp = reinterpret_cast<const float4*>(y_pred + (size_t)row0 * 15);
    const float4* gm = reinterpret_cast<const float4*>(mask + (size_t)row0 * 15);
    for (int i = threadIdx.x; i < cnt4; i += 256) {
        reinterpret_cast<float4*>(sT)[i] = gt[i];
        reinterpret_cast<float4*>(sP)[i] = gp[i];
        reinterpret_cast<float4*>(sM)[i] = gm[i];
    }
    for (int i = (cnt4 << 2) + threadIdx.x; i < cnt; i += 256) {
        sT[i] = y_true[(size_t)row0 * 15 + i];
        sP[i] = y_pred[(size_t)row0 * 15 + i];
        sM[i] = mask[(size_t)row0 * 15 + i];
    }
    __syncthreads();

    float result = 0.0f;
    const int row = row0 + threadIdx.x;
    if (row < n) {
        float T[15], P[15];
        const float* st = sT + threadIdx.x * 15;
        const float* sp = sP + threadIdx.x * 15;
        const float* sm = sM + threadIdx.x * 15;
#pragma unroll
        for (int c = 0; c < 15; c++) { T[c] = st[c]; P[c] = sp[c]; }

        // ---- atom MSE part ----
        float num_a = 0.f, den_a = 0.f;
        int avm = 0;  // 5-bit atom_valid mask
#pragma unroll
        for (int a = 0; a < 5; a++) {
            float se = 0.f;
            bool av = false;
#pragma unroll
            for (int c = 0; c < 3; c++) {
                float m = sm[a * 3 + c];
                float d = T[a * 3 + c] - P[a * 3 + c];
                se = fmaf(d * d, m, se);
                av = av || (m > 0.f);
            }
            if (av) { num_a += se; den_a += 1.f; avm |= (1 << a); }
        }
        result = num_a / (den_a + EPSV);

        // ---- angle part ----
        float2 gb = *reinterpret_cast<const float2*>(xin + (size_t)row * 38 + 36);
        float bead = gb.x, gate = gb.y;
        if (!isfinite(gate)) gate = 0.f;
        if (!isfinite(bead)) bead = 0.f;
        gate = fminf(fmaxf(gate, -64.f), 64.f);
        bead = fminf(fmaxf(bead, -64.f), 64.f);
        int res_id = min(max((int)rintf(gate) - 1, 0), NEXP - 1);
        int bead_id = min(max((int)rintf(bead), 0), NBEAD - 1);

        int4 pk = ptbl[res_id * NBEAD + bead_id];
        unsigned pw0 = (unsigned)pk.x, pw1 = (unsigned)pk.y;
        unsigned pw2 = (unsigned)pk.z, pw3 = (unsigned)pk.w;

        float num_g = 0.f, den_g = 0.f;
#pragma unroll
        for (int t = 0; t < 8; t++) {
            unsigned wrd = (t < 2) ? pw0 : (t < 4) ? pw1 : (t < 6) ? pw2 : pw3;
            unsigned e = (wrd >> ((t & 1) * 16)) & 0xffffu;
            int ii = e & 7, jj = (e >> 3) & 7, kk = (e >> 6) & 7;
            bool wok = ((e >> 9) & 1u) != 0u;

            float tix, tiy, tiz, tjx, tjy, tjz, tkx, tky, tkz;
            sel5(T, ii, tix, tiy, tiz);
            sel5(T, jj, tjx, tjy, tjz);
            sel5(T, kk, tkx, tky, tkz);
            float pix, piy, piz, pjx, pjy, pjz, pkx, pky, pkz;
            sel5(P, ii, pix, piy, piz);
            sel5(P, jj, pjx, pjy, pjz);
            sel5(P, kk, pkx, pky, pkz);

            float v1tx = tix - tjx, v1ty = tiy - tjy, v1tz = tiz - tjz;
            float v2tx = tkx - tjx, v2ty = tky - tjy, v2tz = tkz - tjz;
            float v1px = pix - pjx, v1py = piy - pjy, v1pz = piz - pjz;
            float v2px = pkx - pjx, v2py = pky - pjy, v2pz = pkz - pjz;

            float l1t = v1tx * v1tx + v1ty * v1ty + v1tz * v1tz;
            float l2t = v2tx * v2tx + v2ty * v2ty + v2tz * v2tz;
            float l1p = v1px * v1px + v1py * v1py + v1pz * v1pz;
            float l2p = v2px * v2px + v2py * v2py + v2pz * v2pz;

            bool valid = wok && ((avm >> ii) & 1) && ((avm >> jj) & 1) && ((avm >> kk) & 1) &&
                         (l1t > ML2) && (l2t > ML2) && (l1p > ML2) && (l2p > ML2);

            float rt = rsqrtf(fmaxf(l1t, ML2)) * rsqrtf(fmaxf(l2t, ML2));
            float rp = rsqrtf(fmaxf(l1p, ML2)) * rsqrtf(fmaxf(l2p, ML2));

            float dott = v1tx * v2tx + v1ty * v2ty + v1tz * v2tz;
            float dotp = v1px * v2px + v1py * v2py + v1pz * v2pz;
            float cost = fminf(fmaxf(dott * rt, -1.f + 1e-6f), 1.f - 1e-6f);
            float cosp = fminf(fmaxf(dotp * rp, -1.f + 1e-6f), 1.f - 1e-6f);

            float cxt = v1ty * v2tz - v1tz * v2ty;
            float cyt = v1tz * v2tx - v1tx * v2tz;
            float czt = v1tx * v2ty - v1ty * v2tx;
            float sint = sqrtf(cxt * cxt + cyt * cyt + czt * czt) * rt;
            float cxp = v1py * v2pz - v1pz * v2py;
            float cyp = v1pz * v2px - v1px * v2pz;
            float czp = v1px * v2py - v1py * v2px;
            float sinp = sqrtf(cxp * cxp + cyp * cyp + czp * czp) * rp;

            float dc = cosp - cost, dsn = sinp - sint;
            float pa = dc * dc + dsn * dsn;
            if (valid) { num_g += pa; den_g += 1.f; }
        }
        result += num_g / (den_g + EPSV);
    }

    // ---- block reduction ----
#pragma unroll
    for (int off = 32; off > 0; off >>= 1)
        result += __shfl_down(result, off, 64);
    int lane = threadIdx.x & 63, wv = threadIdx.x >> 6;
    if (lane == 0) red[wv] = result;
    __syncthreads();
    if (threadIdx.x == 0) {
        float s = red[0] + red[1] + red[2] + red[3];
        atomicAdd(out, s * inv_n);
    }
}

extern "C" void kernel_launch(void* const* d_in, const int* in_sizes, int n_in,
                              void* d_out, int out_size, void* d_ws, size_t ws_size,
                              hipStream_t stream) {
    const float* x = (const float*)d_in[0];
    const float* y_true = (const float*)d_in[1];
    const float* y_pred = (const float*)d_in[2];
    const float* mask = (const float*)d_in[3];
    const int* trip = (const int*)d_in[4];
    const int* valid = (const int*)d_in[5];
    float* out = (float*)d_out;

    const int n = in_sizes[1] / 15;  // N rows (y_true is N x 15)
    int4* ptbl = (int4*)d_ws;        // 72 x 16B = 1152 bytes

    hipMemsetAsync(out, 0, sizeof(float), stream);
    pack_tables<<<1, 128, 0, stream>>>(trip, valid, ptbl);
    const int blocks = (n + 255) / 256;
    loss_kernel<<<blocks, 256, 0, stream>>>(x, y_true, y_pred, mask, ptbl, out, n,
                                            1.0f / (float)n);
}

// Round 2
// 193.927 us; speedup vs baseline: 1.0216x; 1.0216x over previous
//
#include <hip/hip_runtime.h>
#include <math.h>

#define NATOMS 5
#define NEXP 18
#define NBEAD 4
#define EPSV 1e-8f
#define ML2 (0.02f * 0.02f)

// Select atom idx (0..4) from a register-resident [5][3] array -> v_cmp + cndmask chains.
__device__ __forceinline__ void sel5(const float* a, int idx, float& vx, float& vy, float& vz) {
    vx = a[0]; vy = a[1]; vz = a[2];
#pragma unroll
    for (int q = 1; q < 5; q++) {
        bool c = (idx == q);
        vx = c ? a[3 * q + 0] : vx;
        vy = c ? a[3 * q + 1] : vy;
        vz = c ? a[3 * q + 2] : vz;
    }
}

// LDS budget: sT+sP 30720 + sMask 1024 + sTbl 864 + red 16 = 32640 B
// -> 5 blocks/CU (160 KiB / 32.7 KiB), 20 waves/CU. launch_bounds(256,5) caps VGPR<=102.
__global__ __launch_bounds__(256, 5) void loss_kernel(
    const float* __restrict__ xin, const float* __restrict__ y_true,
    const float* __restrict__ y_pred, const float* __restrict__ mask,
    const int* __restrict__ trip, const int* __restrict__ valid,
    float* __restrict__ out, int n, float inv_n) {
    __shared__ float sT[3840];            // 256 rows x 15
    __shared__ float sP[3840];
    __shared__ unsigned sMask[256];       // 15 validity bits per row (mask is binary)
    __shared__ unsigned sTbl[72][3];      // 8 triplets x 10 bits packed per (expert,bead)
    __shared__ float red[4];

    const int tid = threadIdx.x;

    // --- build packed triplet table + zero row masks ---
    sMask[tid] = 0u;
    if (tid < NEXP * NBEAD) {
        unsigned w0 = 0u, w1 = 0u, w2 = 0u;
#pragma unroll
        for (int t = 0; t < 8; t++) {
            int b = tid * 8 + t;
            int i = trip[b * 3 + 0], j = trip[b * 3 + 1], k = trip[b * 3 + 2];
            unsigned ok = (i >= 0 && j >= 0 && k >= 0 && valid[b] > 0) ? 1u : 0u;
            unsigned ic = (unsigned)min(max(i, 0), NATOMS - 1);
            unsigned jc = (unsigned)min(max(j, 0), NATOMS - 1);
            unsigned kc = (unsigned)min(max(k, 0), NATOMS - 1);
            unsigned e = ic | (jc << 3) | (kc << 6) | (ok << 9);
            if (t < 3) w0 |= e << (t * 10);
            else if (t < 6) w1 |= e << ((t - 3) * 10);
            else w2 |= e << ((t - 6) * 10);
        }
        sTbl[tid][0] = w0; sTbl[tid][1] = w1; sTbl[tid][2] = w2;
    }
    __syncthreads();

    // --- coalesced float4 staging of y_true/y_pred; mask folded to bits ---
    const int row0 = blockIdx.x * 256;
    int rows = n - row0;
    if (rows > 256) rows = 256;
    const int cnt = rows * 15;
    const int cnt4 = cnt >> 2;
    const size_t base = (size_t)row0 * 15;

    const float4* gt = reinterpret_cast<const float4*>(y_true + base);
    const float4* gp = reinterpret_cast<const float4*>(y_pred + base);
    const float4* gm = reinterpret_cast<const float4*>(mask + base);
    for (int i = tid; i < cnt4; i += 256) {
        float4 t4 = gt[i];
        float4 p4 = gp[i];
        float4 m4 = gm[i];
        reinterpret_cast<float4*>(sT)[i] = t4;
        reinterpret_cast<float4*>(sP)[i] = p4;
        int e = i << 2;
        int r = e / 15;
        int p = e - r * 15;
        unsigned b0 = (m4.x > 0.f ? 1u : 0u) | (m4.y > 0.f ? 2u : 0u) |
                      (m4.z > 0.f ? 4u : 0u) | (m4.w > 0.f ? 8u : 0u);
        unsigned sh = b0 << p;               // bits land at positions p..p+3
        unsigned lo = sh & 0x7fffu;          // row r
        unsigned hi = sh >> 15;              // spill into row r+1
        atomicOr(&sMask[r], lo);
        if (hi) atomicOr(&sMask[r + 1], hi);
    }
    for (int i = (cnt4 << 2) + tid; i < cnt; i += 256) {
        sT[i] = y_true[base + i];
        sP[i] = y_pred[base + i];
        if (mask[base + i] > 0.f) {
            int r = i / 15;
            atomicOr(&sMask[r], 1u << (i - r * 15));
        }
    }
    __syncthreads();

    float result = 0.0f;
    const int row = row0 + tid;
    if (row < n) {
        float T[15], P[15];
        const float* st = sT + tid * 15;   // stride 15 (odd) -> 2-way bank alias = free
        const float* sp = sP + tid * 15;
#pragma unroll
        for (int c = 0; c < 15; c++) { T[c] = st[c]; P[c] = sp[c]; }
        const unsigned mrow = sMask[tid];

        // ---- atom MSE ----
        float num_a = 0.f, den_a = 0.f;
        int avm = 0;
#pragma unroll
        for (int a = 0; a < 5; a++) {
            unsigned mb = (mrow >> (3 * a)) & 7u;
            float se = 0.f;
#pragma unroll
            for (int c = 0; c < 3; c++) {
                float d = T[3 * a + c] - P[3 * a + c];
                se += ((mb >> c) & 1u) ? d * d : 0.f;  // mask is binary -> exact
            }
            if (mb) { num_a += se; den_a += 1.f; avm |= (1 << a); }
        }
        result = num_a / (den_a + EPSV);

        // ---- angle part ----
        float2 gb = *reinterpret_cast<const float2*>(xin + (size_t)row * 38 + 36);
        float bead = gb.x, gate = gb.y;
        gate = isfinite(gate) ? gate : 0.f;
        bead = isfinite(bead) ? bead : 0.f;
        gate = fminf(fmaxf(gate, -1e6f), 1e6f);
        bead = fminf(fmaxf(bead, -1e6f), 1e6f);
        int res_id = min(max((int)rintf(gate) - 1, 0), NEXP - 1);
        int bead_id = min(max((int)rintf(bead), 0), NBEAD - 1);
        int combo = res_id * NBEAD + bead_id;
        unsigned w0 = sTbl[combo][0], w1 = sTbl[combo][1], w2 = sTbl[combo][2];

        float num_g = 0.f, den_g = 0.f;
#pragma unroll
        for (int t = 0; t < 8; t++) {
            unsigned wrd = (t < 3) ? w0 : (t < 6) ? w1 : w2;
            int sh = (t < 3) ? t : (t < 6) ? (t - 3) : (t - 6);
            unsigned e = (wrd >> (sh * 10)) & 0x3ffu;
            int ii = e & 7, jj = (e >> 3) & 7, kk = (e >> 6) & 7;
            bool wok = ((e >> 9) & 1u) != 0u;

            float tix, tiy, tiz, tjx, tjy, tjz, tkx, tky, tkz;
            sel5(T, ii, tix, tiy, tiz);
            sel5(T, jj, tjx, tjy, tjz);
            sel5(T, kk, tkx, tky, tkz);
            float pix, piy, piz, pjx, pjy, pjz, pkx, pky, pkz;
            sel5(P, ii, pix, piy, piz);
            sel5(P, jj, pjx, pjy, pjz);
            sel5(P, kk, pkx, pky, pkz);

            float v1tx = tix - tjx, v1ty = tiy - tjy, v1tz = tiz - tjz;
            float v2tx = tkx - tjx, v2ty = tky - tjy, v2tz = tkz - tjz;
            float v1px = pix - pjx, v1py = piy - pjy, v1pz = piz - pjz;
            float v2px = pkx - pjx, v2py = pky - pjy, v2pz = pkz - pjz;

            float l1t = fmaf(v1tx, v1tx, fmaf(v1ty, v1ty, v1tz * v1tz));
            float l2t = fmaf(v2tx, v2tx, fmaf(v2ty, v2ty, v2tz * v2tz));
            float l1p = fmaf(v1px, v1px, fmaf(v1py, v1py, v1pz * v1pz));
            float l2p = fmaf(v2px, v2px, fmaf(v2py, v2py, v2pz * v2pz));

            bool valid = wok && ((avm >> ii) & 1) && ((avm >> jj) & 1) && ((avm >> kk) & 1) &&
                         (l1t > ML2) && (l2t > ML2) && (l1p > ML2) && (l2p > ML2);

            // 1/sqrt(l1)*1/sqrt(l2) == 1/sqrt(l1*l2); clamps match ref's max(l,ml2)
            float rt = __builtin_amdgcn_rsqf(fmaxf(l1t, ML2) * fmaxf(l2t, ML2));
            float rp = __builtin_amdgcn_rsqf(fmaxf(l1p, ML2) * fmaxf(l2p, ML2));

            float dott = fmaf(v1tx, v2tx, fmaf(v1ty, v2ty, v1tz * v2tz));
            float dotp = fmaf(v1px, v2px, fmaf(v1py, v2py, v1pz * v2pz));
            float cut = dott * rt;
            float cup = dotp * rp;
            float cost = fminf(fmaxf(cut, -1.f + 1e-6f), 1.f - 1e-6f);
            float cosp = fminf(fmaxf(cup, -1.f + 1e-6f), 1.f - 1e-6f);
            // |u1 x u2| = sqrt(1 - cos^2) (unclipped cos), replaces cross product + norm
            float s2t = fmaxf(fmaf(-cut, cut, 1.f), 0.f);
            float s2p = fmaxf(fmaf(-cup, cup, 1.f), 0.f);
            float sint = __builtin_amdgcn_sqrtf(s2t);
            float sinp = __builtin_amdgcn_sqrtf(s2p);

            float dc = cosp - cost, dsn = sinp - sint;
            if (valid) { num_g += fmaf(dc, dc, dsn * dsn); den_g += 1.f; }
        }
        result += num_g / (den_g + EPSV);
    }

    // ---- block reduction ----
#pragma unroll
    for (int off = 32; off > 0; off >>= 1)
        result += __shfl_down(result, off, 64);
    int lane = tid & 63, wv = tid >> 6;
    if (lane == 0) red[wv] = result;
    __syncthreads();
    if (tid == 0) {
        float s = red[0] + red[1] + red[2] + red[3];
        atomicAdd(out, s * inv_n);
    }
}

extern "C" void kernel_launch(void* const* d_in, const int* in_sizes, int n_in,
                              void* d_out, int out_size, void* d_ws, size_t ws_size,
                              hipStream_t stream) {
    const float* x = (const float*)d_in[0];
    const float* y_true = (const float*)d_in[1];
    const float* y_pred = (const float*)d_in[2];
    const float* mask = (const float*)d_in[3];
    const int* trip = (const int*)d_in[4];
    const int* valid = (const int*)d_in[5];
    float* out = (float*)d_out;

    const int n = in_sizes[1] / 15;  // N rows (y_true is N x 15)

    hipMemsetAsync(out, 0, sizeof(float), stream);
    const int blocks = (n + 255) / 256;
    loss_kernel<<<blocks, 256, 0, stream>>>(x, y_true, y_pred, mask, trip, valid, out, n,
                                            1.0f / (float)n);
}